// Round 9
// baseline (971.031 us; speedup 1.0000x reference)
//
#include <hip/hip_runtime.h>
#include <hip/hip_bf16.h>

#define B_  16
#define C_  1024
#define NP_ 512
#define DM_ 512
#define H_  8
#define D_  64
#define BC_ 16384

#define PAVG_STRIDE 17
#define NBMAX 4          // S-chunk <=128 MB -> Infinity-Cache resident

// 16x8-micro fp32 GEMM tile: 256x128 block, 256 threads, BK=16
#define BM2 256
#define BN2 128
#define LDA2 260
#define LDB2 132

typedef unsigned long long ull;
typedef unsigned short u16;
using short8 = __attribute__((ext_vector_type(8))) short;
using f32x4  = __attribute__((ext_vector_type(4))) float;

__device__ __forceinline__ u16 f2bf(float x) {
    __hip_bfloat16 h = __float2bfloat16(x);
    return *reinterpret_cast<u16*>(&h);
}
__device__ __forceinline__ float bf2f(u16 v) {
    return __uint_as_float(((unsigned)v) << 16);
}

// ---- fp32 tile GEMM core, 16x8 micro-tile: acc += A(MxK) * B(NxK)^T ----
// LDS-BW math: per kk a wave does 128 FMA (256 cyc) vs 6 ds_read_b128 (72 cyc);
// 4 waves/CU -> 288 LDS-cyc per 256 -> ~89% VALU ceiling (vs 67% for 8x8).
__device__ __forceinline__ void sgemm_tile_16x8(const float* __restrict__ A,
                                                const float* __restrict__ Bm,
                                                int Kk, int lda, int ldb,
                                                int row0, int col0,
                                                float* __restrict__ As, float* __restrict__ Bs,
                                                float (&acc)[16][8])
{
    const int tid = threadIdx.x;
    const int ty = tid >> 4;       // 0..15 -> 16-row group
    const int tx = tid & 15;       // 0..15 -> 8-col group
    for (int k0 = 0; k0 < Kk; k0 += 16) {
#pragma unroll
        for (int v = 0; v < 4; ++v) {          // stage A: 256 rows x 16 k
            const int idx = tid + v * 256;     // 0..1023
            const int m = idx >> 2;            // 0..255
            const int kq = (idx & 3) << 2;     // 0,4,8,12
            const float4 av = *(const float4*)(A + (size_t)(row0 + m) * lda + k0 + kq);
            As[(kq + 0) * LDA2 + m] = av.x;
            As[(kq + 1) * LDA2 + m] = av.y;
            As[(kq + 2) * LDA2 + m] = av.z;
            As[(kq + 3) * LDA2 + m] = av.w;
        }
#pragma unroll
        for (int v = 0; v < 2; ++v) {          // stage B: 128 rows x 16 k
            const int idx = tid + v * 256;     // 0..511
            const int m = idx >> 2;            // 0..127
            const int kq = (idx & 3) << 2;
            const float4 bv = *(const float4*)(Bm + (size_t)(col0 + m) * ldb + k0 + kq);
            Bs[(kq + 0) * LDB2 + m] = bv.x;
            Bs[(kq + 1) * LDB2 + m] = bv.y;
            Bs[(kq + 2) * LDB2 + m] = bv.z;
            Bs[(kq + 3) * LDB2 + m] = bv.w;
        }
        __syncthreads();
#pragma unroll
        for (int kk = 0; kk < 16; ++kk) {
            const float* Ar = As + kk * LDA2 + ty * 16;
            const float* Br = Bs + kk * LDB2 + tx * 8;
            float a[16], bb[8];
            *(float4*)(a + 0)  = *(const float4*)(Ar + 0);
            *(float4*)(a + 4)  = *(const float4*)(Ar + 4);
            *(float4*)(a + 8)  = *(const float4*)(Ar + 8);
            *(float4*)(a + 12) = *(const float4*)(Ar + 12);
            *(float4*)(bb + 0) = *(const float4*)(Br + 0);
            *(float4*)(bb + 4) = *(const float4*)(Br + 4);
#pragma unroll
            for (int ii = 0; ii < 16; ++ii)
#pragma unroll
                for (int jj = 0; jj < 8; ++jj)
                    acc[ii][jj] = fmaf(a[ii], bb[jj], acc[ii][jj]);
        }
        __syncthreads();
    }
}

// ---- kernel 0: generic fp32 -> bf16 convert (grid = n/1024) ----
__global__ __launch_bounds__(256) void f32_to_bf16(const float* __restrict__ S, u16* __restrict__ Dp)
{
    const int i = (blockIdx.x * 256 + threadIdx.x) * 4;
    const float4 v = *(const float4*)(S + i);
    ushort4 o;
    o.x = f2bf(v.x); o.y = f2bf(v.y); o.z = f2bf(v.z); o.w = f2bf(v.w);
    *(ushort4*)(Dp + i) = o;
}

// ---- kernel 1: Q/K projections fp32 (z in {0,1}), FULL 16 batches ----
__global__ __launch_bounds__(256, 2) void qk_gemm(const float* __restrict__ Mi,
    const float* __restrict__ Wq, const float* __restrict__ Wk,
    float* __restrict__ Q, float* __restrict__ K)
{
    __shared__ float As[16 * LDA2];
    __shared__ float Bs[16 * LDB2];
    const int z = blockIdx.z;
    const float* W = (z == 0) ? Wq : Wk;
    float* C = (z == 0) ? Q : K;
    const int row0 = blockIdx.x * BM2, col0 = blockIdx.y * BN2;
    float acc[16][8] = {};
    sgemm_tile_16x8(Mi, W, NP_, NP_, NP_, row0, col0, As, Bs, acc);
    const int ty = threadIdx.x >> 4, tx = threadIdx.x & 15;
#pragma unroll
    for (int i = 0; i < 16; ++i) {
        const int gr = row0 + ty * 16 + i;
        float* p = C + (size_t)gr * DM_ + col0 + tx * 8;
        *(float4*)(p + 0) = make_float4(acc[i][0], acc[i][1], acc[i][2], acc[i][3]);
        *(float4*)(p + 4) = make_float4(acc[i][4], acc[i][5], acc[i][6], acc[i][7]);
    }
}

// ---- kernel 1b: V projection via bf16 MFMA: V = bf16(Mi) @ bf16(Wv)^T ----
#define FLDS 40
__global__ __launch_bounds__(256) void v_gemm_mfma(const u16* __restrict__ Mib,
    const u16* __restrict__ Wvb, u16* __restrict__ Vb)
{
    __shared__ u16 As[128 * FLDS];
    __shared__ u16 Bs[128 * FLDS];
    const int tid = threadIdx.x, lane = tid & 63, w = tid >> 6;
    const int wm = w >> 1, wn = w & 1;
    const int row0 = blockIdx.x * 128, col0 = blockIdx.y * 128;

    f32x4 acc[4][4];
#pragma unroll
    for (int mt = 0; mt < 4; ++mt)
#pragma unroll
        for (int nt = 0; nt < 4; ++nt)
            acc[mt][nt] = (f32x4){0.f, 0.f, 0.f, 0.f};

    const int q8 = (lane >> 4) * 8, l16 = lane & 15;
    for (int k0 = 0; k0 < NP_; k0 += 32) {
#pragma unroll
        for (int rep = 0; rep < 2; ++rep) {
            const int c = tid + rep * 256;
            const int row = c >> 2, kq = (c & 3) * 8;
            *(uint4*)(&As[row * FLDS + kq]) = *(const uint4*)(Mib + (size_t)(row0 + row) * NP_ + k0 + kq);
            *(uint4*)(&Bs[row * FLDS + kq]) = *(const uint4*)(Wvb + (size_t)(col0 + row) * NP_ + k0 + kq);
        }
        __syncthreads();
        short8 a[4], bfr[4];
#pragma unroll
        for (int mt = 0; mt < 4; ++mt)
            a[mt] = *(const short8*)(&As[(wm * 64 + mt * 16 + l16) * FLDS + q8]);
#pragma unroll
        for (int nt = 0; nt < 4; ++nt)
            bfr[nt] = *(const short8*)(&Bs[(wn * 64 + nt * 16 + l16) * FLDS + q8]);
#pragma unroll
        for (int mt = 0; mt < 4; ++mt)
#pragma unroll
            for (int nt = 0; nt < 4; ++nt)
                acc[mt][nt] = __builtin_amdgcn_mfma_f32_16x16x32_bf16(a[mt], bfr[nt], acc[mt][nt], 0, 0, 0);
        __syncthreads();
    }
    const int quad = lane >> 4;
#pragma unroll
    for (int mt = 0; mt < 4; ++mt)
#pragma unroll
        for (int nt = 0; nt < 4; ++nt) {
            const int n = col0 + wn * 64 + nt * 16 + l16;
#pragma unroll
            for (int reg = 0; reg < 4; ++reg) {
                const int m = row0 + wm * 64 + mt * 16 + quad * 4 + reg;
                Vb[(size_t)m * DM_ + n] = f2bf(acc[mt][nt][reg]);
            }
        }
}

// ---- kernel 2: per-(bl,h) scores S = (QK^T)*scale (K=64), 256x128 tiles ----
__global__ __launch_bounds__(256, 2) void score_gemm(const float* __restrict__ Q,
    const float* __restrict__ K, float* __restrict__ S)
{
    __shared__ float As[16 * LDA2];
    __shared__ float Bs[16 * LDB2];
    const int z = blockIdx.z;
    const int h = z & 7, bl = z >> 3;
    const float* A  = Q + (size_t)bl * C_ * DM_ + h * D_;
    const float* Bp = K + (size_t)bl * C_ * DM_ + h * D_;
    float* C = S + (size_t)z * C_ * C_;
    const int row0 = blockIdx.x * BM2, col0 = blockIdx.y * BN2;
    float acc[16][8] = {};
    sgemm_tile_16x8(A, Bp, D_, DM_, DM_, row0, col0, As, Bs, acc);
    const int ty = threadIdx.x >> 4, tx = threadIdx.x & 15;
#pragma unroll
    for (int i = 0; i < 16; ++i) {
        const int gr = row0 + ty * 16 + i;
        float* p = C + (size_t)gr * C_ + col0 + tx * 8;
        *(float4*)(p + 0) = make_float4(acc[i][0] * 0.125f, acc[i][1] * 0.125f,
                                        acc[i][2] * 0.125f, acc[i][3] * 0.125f);
        *(float4*)(p + 4) = make_float4(acc[i][4] * 0.125f, acc[i][5] * 0.125f,
                                        acc[i][6] * 0.125f, acc[i][7] * 0.125f);
    }
}

// ---- packing: (monotone(value) << 32) | (1023 - j) ----
__device__ __forceinline__ ull pack1(float f, int j) {
    unsigned b = __float_as_uint(f);
    unsigned u = b ^ ((unsigned)((int)b >> 31) | 0x80000000u);
    return ((ull)u << 32) | (unsigned)(1023 - j);
}
__device__ __forceinline__ float unpack_val(ull e) {
    unsigned u = (unsigned)(e >> 32);
    unsigned b = u ^ ((u & 0x80000000u) ? 0x80000000u : 0xFFFFFFFFu);
    return __uint_as_float(b);
}
__device__ __forceinline__ int unpack_j(ull e) {
    return 1023 - (int)(e & 0xFFFFFFFFu);
}

// ---- exact wave-wide top-16 of 1024 via tau-filter + candidate sort ----
__device__ __forceinline__ void topk16_fast(float (&f)[16], const int lane,
                                            ull* candw, ull (&out)[16])
{
    float mv = f[0];
#pragma unroll
    for (int r = 1; r < 16; ++r) mv = fmaxf(mv, f[r]);
#pragma unroll
    for (int k = 2; k <= 64; k <<= 1) {
#pragma unroll
        for (int j = k >> 1; j > 0; j >>= 1) {
            const float t = __shfl_xor(mv, j);
            const bool kmax = ((lane & k) == 0) == ((lane & j) == 0);
            mv = kmax ? fmaxf(mv, t) : fminf(mv, t);
        }
    }
    const float tau = __shfl(mv, 15);
    unsigned msk = 0u;
#pragma unroll
    for (int r = 0; r < 16; ++r) msk |= (f[r] >= tau) ? (1u << r) : 0u;
    const int cnt = __popc(msk);
    int incl = cnt;
#pragma unroll
    for (int off = 1; off < 64; off <<= 1) {
        const int t = __shfl_up(incl, off);
        incl += (lane >= off) ? t : 0;
    }
    const int total = __shfl(incl, 63);

    if (total <= 64) {
        int ofs = incl - cnt;
        unsigned m = msk;
        while (m) {
            const int r = __ffs(m) - 1;
            m &= m - 1;
            candw[ofs++] = pack1(f[r], (lane << 4) + r);
        }
        ull e = candw[lane];
        if (lane >= total) e = 0ull;
#pragma unroll
        for (int k = 2; k <= 64; k <<= 1) {
#pragma unroll
            for (int j = k >> 1; j > 0; j >>= 1) {
                const ull p = __shfl_xor(e, j);
                const bool kmax = ((lane & k) == 0) == ((lane & j) == 0);
                if ((p > e) == kmax) e = p;
            }
        }
#pragma unroll
        for (int t = 0; t < 16; ++t) out[t] = __shfl(e, t);
    } else {
        for (int it = 0; it < 16; ++it) {
            float bv = f[0]; int bj = lane << 4;
#pragma unroll
            for (int r = 1; r < 16; ++r)
                if (f[r] > bv) { bv = f[r]; bj = (lane << 4) + r; }
#pragma unroll
            for (int off = 32; off >= 1; off >>= 1) {
                const float ov = __shfl_xor(bv, off);
                const int   oj = __shfl_xor(bj, off);
                if (ov > bv || (ov == bv && oj < bj)) { bv = ov; bj = oj; }
            }
            out[it] = pack1(bv, bj);
            if ((bj >> 4) == lane) f[bj & 15] = -3.402823466e38f;
        }
    }
}

__device__ __forceinline__ void softmax16p(const ull (&e)[16], float (&wv)[16], int (&jl)[16])
{
    float vals[16];
#pragma unroll
    for (int t = 0; t < 16; ++t) vals[t] = unpack_val(e[t]);
    const float mx = vals[0];
    float Z = 0.0f;
#pragma unroll
    for (int t = 0; t < 16; ++t) { wv[t] = __expf(vals[t] - mx); Z += wv[t]; }
    const float inv = 1.0f / Z;
#pragma unroll
    for (int t = 0; t < 16; ++t) { wv[t] *= inv; jl[t] = unpack_j(e[t]); }
}

// ---- kernel 3: per-row topk + softmax + sparse AV(bf16) + A output ----
__global__ __launch_bounds__(256) void topk_attn(const float* __restrict__ S,
    const u16* __restrict__ V, u16* __restrict__ O,
    float* __restrict__ Aout, int b0)
{
    __shared__ float pavg[4 * 64 * PAVG_STRIDE];
    __shared__ float arow[1024];
    __shared__ ull   cand[4][64];

    const int tid = threadIdx.x, lane = tid & 63, w = tid >> 6;
    const int rb = blockIdx.x, bl = rb >> 10, i = rb & 1023;
    const int b = b0 + bl;

    const float* r1 = S + ((size_t)(bl * 8 + w) * C_ + i) * C_ + lane * 16;
    const float* r2 = S + ((size_t)(bl * 8 + w + 4) * C_ + i) * C_ + lane * 16;
    float f1[16], f2[16];
#pragma unroll
    for (int q = 0; q < 4; ++q) {
        const float4 x = *(const float4*)(r1 + q * 4);
        f1[q * 4 + 0] = x.x; f1[q * 4 + 1] = x.y; f1[q * 4 + 2] = x.z; f1[q * 4 + 3] = x.w;
        const float4 y = *(const float4*)(r2 + q * 4);
        f2[q * 4 + 0] = y.x; f2[q * 4 + 1] = y.y; f2[q * 4 + 2] = y.z; f2[q * 4 + 3] = y.w;
    }
    {
        float* pw = pavg + w * 64 * PAVG_STRIDE + lane * PAVG_STRIDE;
#pragma unroll
        for (int r = 0; r < 16; ++r) pw[r] = f1[r] + f2[r];
    }
    *(float4*)(arow + tid * 4) = make_float4(0.f, 0.f, 0.f, 0.f);
    __syncthreads();

    {
        ull top[16];
        topk16_fast(f1, lane, cand[w], top);
        float wv[16]; int jl[16];
        softmax16p(top, wv, jl);
        float o = 0.0f;
#pragma unroll
        for (int t = 0; t < 16; ++t)
            o = fmaf(wv[t], bf2f(V[((size_t)(bl * C_ + jl[t])) * DM_ + w * D_ + lane]), o);
        O[((size_t)(bl * C_ + i)) * DM_ + w * D_ + lane] = f2bf(o);
    }
    {
        ull top[16];
        topk16_fast(f2, lane, cand[w], top);
        float wv[16]; int jl[16];
        softmax16p(top, wv, jl);
        float o = 0.0f;
#pragma unroll
        for (int t = 0; t < 16; ++t)
            o = fmaf(wv[t], bf2f(V[((size_t)(bl * C_ + jl[t])) * DM_ + (w + 4) * D_ + lane]), o);
        O[((size_t)(bl * C_ + i)) * DM_ + (w + 4) * D_ + lane] = f2bf(o);
    }
    if (w == 3) {
        float fa[16];
#pragma unroll
        for (int r = 0; r < 16; ++r) {
            fa[r] = pavg[0 * 64 * PAVG_STRIDE + lane * PAVG_STRIDE + r]
                  + pavg[1 * 64 * PAVG_STRIDE + lane * PAVG_STRIDE + r]
                  + pavg[2 * 64 * PAVG_STRIDE + lane * PAVG_STRIDE + r]
                  + pavg[3 * 64 * PAVG_STRIDE + lane * PAVG_STRIDE + r];
        }
        ull top[16];
        topk16_fast(fa, lane, cand[3], top);
        if (lane == 0) {
#pragma unroll
            for (int t = 0; t < 16; ++t) arow[unpack_j(top[t])] = 1.0f;
        }
    }
    __syncthreads();
    *(float4*)(Aout + ((size_t)(b * C_ + i)) * C_ + tid * 4) = *(const float4*)(&arow[tid * 4]);
}

// ---- kernel 4: MFMA bf16, FULL: delta = O @ Wo^T + bo ; M_tilde = M + gate*delta ----
__global__ __launch_bounds__(256) void final_gemm_mfma(const u16* __restrict__ O,
    const u16* __restrict__ Wob, const float* __restrict__ Mi,
    const float* __restrict__ bo, const float* __restrict__ gatep,
    float* __restrict__ out)
{
    __shared__ u16 As[128 * FLDS];
    __shared__ u16 Bs[128 * FLDS];
    const int tid = threadIdx.x, lane = tid & 63, w = tid >> 6;
    const int wm = w >> 1, wn = w & 1;
    const int row0 = blockIdx.x * 128, col0 = blockIdx.y * 128;

    f32x4 acc[4][4];
#pragma unroll
    for (int mt = 0; mt < 4; ++mt)
#pragma unroll
        for (int nt = 0; nt < 4; ++nt)
            acc[mt][nt] = (f32x4){0.f, 0.f, 0.f, 0.f};

    const int q8 = (lane >> 4) * 8, l16 = lane & 15;
    for (int k0 = 0; k0 < DM_; k0 += 32) {
#pragma unroll
        for (int rep = 0; rep < 2; ++rep) {
            const int c = tid + rep * 256;
            const int row = c >> 2, kq = (c & 3) * 8;
            *(uint4*)(&As[row * FLDS + kq]) = *(const uint4*)(O   + (size_t)(row0 + row) * DM_ + k0 + kq);
            *(uint4*)(&Bs[row * FLDS + kq]) = *(const uint4*)(Wob + (size_t)(col0 + row) * DM_ + k0 + kq);
        }
        __syncthreads();
        short8 a[4], bfr[4];
#pragma unroll
        for (int mt = 0; mt < 4; ++mt)
            a[mt] = *(const short8*)(&As[(wm * 64 + mt * 16 + l16) * FLDS + q8]);
#pragma unroll
        for (int nt = 0; nt < 4; ++nt)
            bfr[nt] = *(const short8*)(&Bs[(wn * 64 + nt * 16 + l16) * FLDS + q8]);
#pragma unroll
        for (int mt = 0; mt < 4; ++mt)
#pragma unroll
            for (int nt = 0; nt < 4; ++nt)
                acc[mt][nt] = __builtin_amdgcn_mfma_f32_16x16x32_bf16(a[mt], bfr[nt], acc[mt][nt], 0, 0, 0);
        __syncthreads();
    }

    const float g = gatep[0];
    const int quad = lane >> 4;
#pragma unroll
    for (int mt = 0; mt < 4; ++mt) {
#pragma unroll
        for (int nt = 0; nt < 4; ++nt) {
            const int n = col0 + wn * 64 + nt * 16 + l16;
            const float bon = bo[n];
#pragma unroll
            for (int reg = 0; reg < 4; ++reg) {
                const int m = row0 + wm * 64 + mt * 16 + quad * 4 + reg;
                out[(size_t)m * NP_ + n] = Mi[(size_t)m * NP_ + n] + g * (acc[mt][nt][reg] + bon);
            }
        }
    }
}

extern "C" void kernel_launch(void* const* d_in, const int* in_sizes, int n_in,
                              void* d_out, int out_size, void* d_ws, size_t ws_size,
                              hipStream_t stream)
{
    (void)in_sizes; (void)n_in; (void)out_size;
    const float* Mi   = (const float*)d_in[0];
    const float* Wq   = (const float*)d_in[1];
    const float* Wk   = (const float*)d_in[2];
    const float* Wv   = (const float*)d_in[3];
    const float* Wo   = (const float*)d_in[4];
    const float* bo   = (const float*)d_in[5];
    const float* gate = (const float*)d_in[6];
    float* out  = (float*)d_out;
    float* Aout = out + (size_t)BC_ * NP_;

    // workspace layout (float-slots)
    float* ws = (float*)d_ws;
    u16*   Wob = (u16*)ws;                                     // 512x512 bf16
    u16*   Wvb = (u16*)(ws + 131072);                          // 512x512 bf16
    u16*   Mib = (u16*)(ws + 2 * 131072);                      // BC x 512 bf16
    float* Qf  = ws + 2 * 131072 + (size_t)BC_ * DM_ / 2;      // fp32
    float* Kf  = Qf + (size_t)BC_ * DM_;
    u16*   Vb  = (u16*)(Kf + (size_t)BC_ * DM_);               // bf16 V
    u16*   Of  = (u16*)(Kf + (size_t)BC_ * DM_ + (size_t)BC_ * DM_ / 2);  // bf16 O
    float* Sc  = Kf + (size_t)BC_ * DM_ + (size_t)BC_ * DM_;   // chunked scores

    const size_t fixed = 2 * 131072 + (size_t)BC_ * DM_ / 2 + 3 * (size_t)BC_ * DM_;
    const size_t ws_floats = ws_size / 4;
    size_t avail = (ws_floats > fixed) ? (ws_floats - fixed) : 0;
    int NB = (int)(avail / ((size_t)H_ * C_ * C_));
    if (NB < 1) NB = 1;
    if (NB > NBMAX) NB = NBMAX;

    f32_to_bf16<<<dim3(NP_ * DM_ / 1024), 256, 0, stream>>>(Wo, Wob);
    f32_to_bf16<<<dim3(NP_ * DM_ / 1024), 256, 0, stream>>>(Wv, Wvb);
    f32_to_bf16<<<dim3((int)((size_t)BC_ * NP_ / 1024)), 256, 0, stream>>>(Mi, Mib);

    qk_gemm<<<dim3(BC_ / BM2, DM_ / BN2, 2), 256, 0, stream>>>(Mi, Wq, Wk, Qf, Kf);
    v_gemm_mfma<<<dim3(BC_ / 128, DM_ / 128), 256, 0, stream>>>(Mib, Wvb, Vb);

    for (int b0 = 0; b0 < B_; b0 += NB) {
        const int nb = (B_ - b0 < NB) ? (B_ - b0) : NB;
        score_gemm<<<dim3(C_ / BM2, C_ / BN2, nb * 8), 256, 0, stream>>>(
            Qf + (size_t)b0 * C_ * DM_, Kf + (size_t)b0 * C_ * DM_, Sc);
        topk_attn<<<dim3(nb * C_), 256, 0, stream>>>(
            Sc, Vb + (size_t)b0 * C_ * DM_, Of + (size_t)b0 * C_ * DM_, Aout, b0);
    }

    final_gemm_mfma<<<dim3(BC_ / 128, NP_ / 128), 256, 0, stream>>>(
        Of, Wob, Mi, bo, gate, out);
}

// Round 10
// 874.650 us; speedup vs baseline: 1.1102x; 1.1102x over previous
//
#include <hip/hip_runtime.h>
#include <hip/hip_bf16.h>

#define B_  16
#define C_  1024
#define NP_ 512
#define DM_ 512
#define H_  8
#define D_  64
#define BC_ 16384

#define BM 128
#define BN 128
#define LDT 132
#define PAVG_STRIDE 17
#define NBMAX 4          // S-chunk <=128 MB -> Infinity-Cache resident

typedef unsigned long long ull;
typedef unsigned short u16;
using short8 = __attribute__((ext_vector_type(8))) short;
using f32x4  = __attribute__((ext_vector_type(4))) float;

__device__ __forceinline__ u16 f2bf(float x) {
    __hip_bfloat16 h = __float2bfloat16(x);
    return *reinterpret_cast<u16*>(&h);
}
__device__ __forceinline__ float bf2f(u16 v) {
    return __uint_as_float(((unsigned)v) << 16);
}

// ---- fp32 tile GEMM core, 8x8 micro, BK=16 (measured best: 69% VALU, no spill) ----
// acc >= 128 fp32/thread spills on this compiler (r9: VGPR capped at 128, scratch
// traffic doubled WRITE_SIZE). Keep acc at 64.
__device__ __forceinline__ void sgemm_tile(const float* __restrict__ A,
                                           const float* __restrict__ Bm,
                                           int Kk, int lda, int ldb,
                                           int row0, int col0,
                                           float* __restrict__ As, float* __restrict__ Bs,
                                           float (&acc)[8][8])
{
    const int tid = threadIdx.x;
    const int ty4 = (tid >> 4) << 2;
    const int tx4 = (tid & 15) << 2;
    for (int k0 = 0; k0 < Kk; k0 += 16) {
#pragma unroll
        for (int v = 0; v < 2; ++v) {
            const int i = tid + v * 256;
            const int m = i >> 2;
            const int kq = (i & 3) << 2;
            const float4 av = *(const float4*)(A + (size_t)(row0 + m) * lda + k0 + kq);
            As[(kq + 0) * LDT + m] = av.x;
            As[(kq + 1) * LDT + m] = av.y;
            As[(kq + 2) * LDT + m] = av.z;
            As[(kq + 3) * LDT + m] = av.w;
            const float4 bv = *(const float4*)(Bm + (size_t)(col0 + m) * ldb + k0 + kq);
            Bs[(kq + 0) * LDT + m] = bv.x;
            Bs[(kq + 1) * LDT + m] = bv.y;
            Bs[(kq + 2) * LDT + m] = bv.z;
            Bs[(kq + 3) * LDT + m] = bv.w;
        }
        __syncthreads();
#pragma unroll
        for (int kk = 0; kk < 16; ++kk) {
            const float* Ar = As + kk * LDT;
            const float* Br = Bs + kk * LDT;
            const float4 a0 = *(const float4*)(Ar + ty4);
            const float4 a1 = *(const float4*)(Ar + 64 + ty4);
            const float4 b0 = *(const float4*)(Br + tx4);
            const float4 b1 = *(const float4*)(Br + 64 + tx4);
            const float a[8]  = {a0.x, a0.y, a0.z, a0.w, a1.x, a1.y, a1.z, a1.w};
            const float bb[8] = {b0.x, b0.y, b0.z, b0.w, b1.x, b1.y, b1.z, b1.w};
#pragma unroll
            for (int ii = 0; ii < 8; ++ii)
#pragma unroll
                for (int jj = 0; jj < 8; ++jj)
                    acc[ii][jj] = fmaf(a[ii], bb[jj], acc[ii][jj]);
        }
        __syncthreads();
    }
}

__device__ __forceinline__ int row_of(int r, int ty4) {
    return (r < 4) ? (ty4 + r) : (64 + ty4 + r - 4);
}

// ---- kernel 0: generic fp32 -> bf16 convert (grid = n/1024) ----
__global__ __launch_bounds__(256) void f32_to_bf16(const float* __restrict__ S, u16* __restrict__ Dp)
{
    const int i = (blockIdx.x * 256 + threadIdx.x) * 4;
    const float4 v = *(const float4*)(S + i);
    ushort4 o;
    o.x = f2bf(v.x); o.y = f2bf(v.y); o.z = f2bf(v.z); o.w = f2bf(v.w);
    *(ushort4*)(Dp + i) = o;
}

// ---- kernel 1: Q/K projections fp32 (z in {0,1}), FULL 16 batches ----
__global__ __launch_bounds__(256) void qk_gemm(const float* __restrict__ Mi,
    const float* __restrict__ Wq, const float* __restrict__ Wk,
    float* __restrict__ Q, float* __restrict__ K)
{
    __shared__ float smem[2 * 16 * LDT];
    const int z = blockIdx.z;
    const float* W = (z == 0) ? Wq : Wk;
    float* C = (z == 0) ? Q : K;
    const int row0 = blockIdx.x * BM, col0 = blockIdx.y * BN;
    float acc[8][8] = {};
    sgemm_tile(Mi, W, NP_, NP_, NP_, row0, col0, smem, smem + 16 * LDT, acc);
    const int ty4 = (threadIdx.x >> 4) << 2;
    const int tx4 = (threadIdx.x & 15) << 2;
#pragma unroll
    for (int r = 0; r < 8; ++r) {
        const int gr = row0 + row_of(r, ty4);
        *(float4*)(C + (size_t)gr * DM_ + col0 + tx4) =
            make_float4(acc[r][0], acc[r][1], acc[r][2], acc[r][3]);
        *(float4*)(C + (size_t)gr * DM_ + col0 + 64 + tx4) =
            make_float4(acc[r][4], acc[r][5], acc[r][6], acc[r][7]);
    }
}

// ---- kernel 1b: V projection via bf16 MFMA: V = bf16(Mi) @ bf16(Wv)^T ----
#define FLDS 40
__global__ __launch_bounds__(256) void v_gemm_mfma(const u16* __restrict__ Mib,
    const u16* __restrict__ Wvb, u16* __restrict__ Vb)
{
    __shared__ u16 As[128 * FLDS];
    __shared__ u16 Bs[128 * FLDS];
    const int tid = threadIdx.x, lane = tid & 63, w = tid >> 6;
    const int wm = w >> 1, wn = w & 1;
    const int row0 = blockIdx.x * 128, col0 = blockIdx.y * 128;

    f32x4 acc[4][4];
#pragma unroll
    for (int mt = 0; mt < 4; ++mt)
#pragma unroll
        for (int nt = 0; nt < 4; ++nt)
            acc[mt][nt] = (f32x4){0.f, 0.f, 0.f, 0.f};

    const int q8 = (lane >> 4) * 8, l16 = lane & 15;
    for (int k0 = 0; k0 < NP_; k0 += 32) {
#pragma unroll
        for (int rep = 0; rep < 2; ++rep) {
            const int c = tid + rep * 256;
            const int row = c >> 2, kq = (c & 3) * 8;
            *(uint4*)(&As[row * FLDS + kq]) = *(const uint4*)(Mib + (size_t)(row0 + row) * NP_ + k0 + kq);
            *(uint4*)(&Bs[row * FLDS + kq]) = *(const uint4*)(Wvb + (size_t)(col0 + row) * NP_ + k0 + kq);
        }
        __syncthreads();
        short8 a[4], bfr[4];
#pragma unroll
        for (int mt = 0; mt < 4; ++mt)
            a[mt] = *(const short8*)(&As[(wm * 64 + mt * 16 + l16) * FLDS + q8]);
#pragma unroll
        for (int nt = 0; nt < 4; ++nt)
            bfr[nt] = *(const short8*)(&Bs[(wn * 64 + nt * 16 + l16) * FLDS + q8]);
#pragma unroll
        for (int mt = 0; mt < 4; ++mt)
#pragma unroll
            for (int nt = 0; nt < 4; ++nt)
                acc[mt][nt] = __builtin_amdgcn_mfma_f32_16x16x32_bf16(a[mt], bfr[nt], acc[mt][nt], 0, 0, 0);
        __syncthreads();
    }
    const int quad = lane >> 4;
#pragma unroll
    for (int mt = 0; mt < 4; ++mt)
#pragma unroll
        for (int nt = 0; nt < 4; ++nt) {
            const int n = col0 + wn * 64 + nt * 16 + l16;
#pragma unroll
            for (int reg = 0; reg < 4; ++reg) {
                const int m = row0 + wm * 64 + mt * 16 + quad * 4 + reg;
                Vb[(size_t)m * DM_ + n] = f2bf(acc[mt][nt][reg]);
            }
        }
}

// ---- kernel 2: per-(bl,h) scores S = (QK^T)*scale (K=64, 4 BK-iters) ----
__global__ __launch_bounds__(256) void score_gemm(const float* __restrict__ Q,
    const float* __restrict__ K, float* __restrict__ S)
{
    __shared__ float smem[2 * 16 * LDT];
    const int z = blockIdx.z;
    const int h = z & 7, bl = z >> 3;
    const float* A  = Q + (size_t)bl * C_ * DM_ + h * D_;
    const float* Bp = K + (size_t)bl * C_ * DM_ + h * D_;
    float* C = S + (size_t)z * C_ * C_;
    const int row0 = blockIdx.x * BM, col0 = blockIdx.y * BN;
    float acc[8][8] = {};
    sgemm_tile(A, Bp, D_, DM_, DM_, row0, col0, smem, smem + 16 * LDT, acc);
    const int ty4 = (threadIdx.x >> 4) << 2;
    const int tx4 = (threadIdx.x & 15) << 2;
#pragma unroll
    for (int r = 0; r < 8; ++r) {
        const int gr = row0 + row_of(r, ty4);
        *(float4*)(C + (size_t)gr * C_ + col0 + tx4) =
            make_float4(acc[r][0] * 0.125f, acc[r][1] * 0.125f, acc[r][2] * 0.125f, acc[r][3] * 0.125f);
        *(float4*)(C + (size_t)gr * C_ + col0 + 64 + tx4) =
            make_float4(acc[r][4] * 0.125f, acc[r][5] * 0.125f, acc[r][6] * 0.125f, acc[r][7] * 0.125f);
    }
}

// ---- packing: (monotone(value) << 32) | (1023 - j) ----
__device__ __forceinline__ ull pack1(float f, int j) {
    unsigned b = __float_as_uint(f);
    unsigned u = b ^ ((unsigned)((int)b >> 31) | 0x80000000u);
    return ((ull)u << 32) | (unsigned)(1023 - j);
}
__device__ __forceinline__ float unpack_val(ull e) {
    unsigned u = (unsigned)(e >> 32);
    unsigned b = u ^ ((u & 0x80000000u) ? 0x80000000u : 0xFFFFFFFFu);
    return __uint_as_float(b);
}
__device__ __forceinline__ int unpack_j(ull e) {
    return 1023 - (int)(e & 0xFFFFFFFFu);
}

// ---- exact wave-wide top-16 of 1024 via tau-filter + candidate sort ----
__device__ __forceinline__ void topk16_fast(float (&f)[16], const int lane,
                                            ull* candw, ull (&out)[16])
{
    float mv = f[0];
#pragma unroll
    for (int r = 1; r < 16; ++r) mv = fmaxf(mv, f[r]);
#pragma unroll
    for (int k = 2; k <= 64; k <<= 1) {
#pragma unroll
        for (int j = k >> 1; j > 0; j >>= 1) {
            const float t = __shfl_xor(mv, j);
            const bool kmax = ((lane & k) == 0) == ((lane & j) == 0);
            mv = kmax ? fmaxf(mv, t) : fminf(mv, t);
        }
    }
    const float tau = __shfl(mv, 15);
    unsigned msk = 0u;
#pragma unroll
    for (int r = 0; r < 16; ++r) msk |= (f[r] >= tau) ? (1u << r) : 0u;
    const int cnt = __popc(msk);
    int incl = cnt;
#pragma unroll
    for (int off = 1; off < 64; off <<= 1) {
        const int t = __shfl_up(incl, off);
        incl += (lane >= off) ? t : 0;
    }
    const int total = __shfl(incl, 63);

    if (total <= 64) {
        int ofs = incl - cnt;
        unsigned m = msk;
        while (m) {
            const int r = __ffs(m) - 1;
            m &= m - 1;
            candw[ofs++] = pack1(f[r], (lane << 4) + r);
        }
        ull e = candw[lane];
        if (lane >= total) e = 0ull;
#pragma unroll
        for (int k = 2; k <= 64; k <<= 1) {
#pragma unroll
            for (int j = k >> 1; j > 0; j >>= 1) {
                const ull p = __shfl_xor(e, j);
                const bool kmax = ((lane & k) == 0) == ((lane & j) == 0);
                if ((p > e) == kmax) e = p;
            }
        }
#pragma unroll
        for (int t = 0; t < 16; ++t) out[t] = __shfl(e, t);
    } else {
        for (int it = 0; it < 16; ++it) {
            float bv = f[0]; int bj = lane << 4;
#pragma unroll
            for (int r = 1; r < 16; ++r)
                if (f[r] > bv) { bv = f[r]; bj = (lane << 4) + r; }
#pragma unroll
            for (int off = 32; off >= 1; off >>= 1) {
                const float ov = __shfl_xor(bv, off);
                const int   oj = __shfl_xor(bj, off);
                if (ov > bv || (ov == bv && oj < bj)) { bv = ov; bj = oj; }
            }
            out[it] = pack1(bv, bj);
            if ((bj >> 4) == lane) f[bj & 15] = -3.402823466e38f;
        }
    }
}

__device__ __forceinline__ void softmax16p(const ull (&e)[16], float (&wv)[16], int (&jl)[16])
{
    float vals[16];
#pragma unroll
    for (int t = 0; t < 16; ++t) vals[t] = unpack_val(e[t]);
    const float mx = vals[0];
    float Z = 0.0f;
#pragma unroll
    for (int t = 0; t < 16; ++t) { wv[t] = __expf(vals[t] - mx); Z += wv[t]; }
    const float inv = 1.0f / Z;
#pragma unroll
    for (int t = 0; t < 16; ++t) { wv[t] *= inv; jl[t] = unpack_j(e[t]); }
}

// ---- kernel 3: per-row topk + softmax + sparse AV(bf16) + A output ----
__global__ __launch_bounds__(256) void topk_attn(const float* __restrict__ S,
    const u16* __restrict__ V, u16* __restrict__ O,
    float* __restrict__ Aout, int b0)
{
    __shared__ float pavg[4 * 64 * PAVG_STRIDE];
    __shared__ float arow[1024];
    __shared__ ull   cand[4][64];

    const int tid = threadIdx.x, lane = tid & 63, w = tid >> 6;
    const int rb = blockIdx.x, bl = rb >> 10, i = rb & 1023;
    const int b = b0 + bl;

    const float* r1 = S + ((size_t)(bl * 8 + w) * C_ + i) * C_ + lane * 16;
    const float* r2 = S + ((size_t)(bl * 8 + w + 4) * C_ + i) * C_ + lane * 16;
    float f1[16], f2[16];
#pragma unroll
    for (int q = 0; q < 4; ++q) {
        const float4 x = *(const float4*)(r1 + q * 4);
        f1[q * 4 + 0] = x.x; f1[q * 4 + 1] = x.y; f1[q * 4 + 2] = x.z; f1[q * 4 + 3] = x.w;
        const float4 y = *(const float4*)(r2 + q * 4);
        f2[q * 4 + 0] = y.x; f2[q * 4 + 1] = y.y; f2[q * 4 + 2] = y.z; f2[q * 4 + 3] = y.w;
    }
    {
        float* pw = pavg + w * 64 * PAVG_STRIDE + lane * PAVG_STRIDE;
#pragma unroll
        for (int r = 0; r < 16; ++r) pw[r] = f1[r] + f2[r];
    }
    *(float4*)(arow + tid * 4) = make_float4(0.f, 0.f, 0.f, 0.f);
    __syncthreads();

    {
        ull top[16];
        topk16_fast(f1, lane, cand[w], top);
        float wv[16]; int jl[16];
        softmax16p(top, wv, jl);
        float o = 0.0f;
#pragma unroll
        for (int t = 0; t < 16; ++t)
            o = fmaf(wv[t], bf2f(V[((size_t)(bl * C_ + jl[t])) * DM_ + w * D_ + lane]), o);
        O[((size_t)(bl * C_ + i)) * DM_ + w * D_ + lane] = f2bf(o);
    }
    {
        ull top[16];
        topk16_fast(f2, lane, cand[w], top);
        float wv[16]; int jl[16];
        softmax16p(top, wv, jl);
        float o = 0.0f;
#pragma unroll
        for (int t = 0; t < 16; ++t)
            o = fmaf(wv[t], bf2f(V[((size_t)(bl * C_ + jl[t])) * DM_ + (w + 4) * D_ + lane]), o);
        O[((size_t)(bl * C_ + i)) * DM_ + (w + 4) * D_ + lane] = f2bf(o);
    }
    if (w == 3) {
        float fa[16];
#pragma unroll
        for (int r = 0; r < 16; ++r) {
            fa[r] = pavg[0 * 64 * PAVG_STRIDE + lane * PAVG_STRIDE + r]
                  + pavg[1 * 64 * PAVG_STRIDE + lane * PAVG_STRIDE + r]
                  + pavg[2 * 64 * PAVG_STRIDE + lane * PAVG_STRIDE + r]
                  + pavg[3 * 64 * PAVG_STRIDE + lane * PAVG_STRIDE + r];
        }
        ull top[16];
        topk16_fast(fa, lane, cand[3], top);
        if (lane == 0) {
#pragma unroll
            for (int t = 0; t < 16; ++t) arow[unpack_j(top[t])] = 1.0f;
        }
    }
    __syncthreads();
    *(float4*)(Aout + ((size_t)(b * C_ + i)) * C_ + tid * 4) = *(const float4*)(&arow[tid * 4]);
}

// ---- kernel 4: MFMA bf16, FULL: delta = O @ Wo^T + bo ; M_tilde = M + gate*delta ----
__global__ __launch_bounds__(256) void final_gemm_mfma(const u16* __restrict__ O,
    const u16* __restrict__ Wob, const float* __restrict__ Mi,
    const float* __restrict__ bo, const float* __restrict__ gatep,
    float* __restrict__ out)
{
    __shared__ u16 As[128 * FLDS];
    __shared__ u16 Bs[128 * FLDS];
    const int tid = threadIdx.x, lane = tid & 63, w = tid >> 6;
    const int wm = w >> 1, wn = w & 1;
    const int row0 = blockIdx.x * 128, col0 = blockIdx.y * 128;

    f32x4 acc[4][4];
#pragma unroll
    for (int mt = 0; mt < 4; ++mt)
#pragma unroll
        for (int nt = 0; nt < 4; ++nt)
            acc[mt][nt] = (f32x4){0.f, 0.f, 0.f, 0.f};

    const int q8 = (lane >> 4) * 8, l16 = lane & 15;
    for (int k0 = 0; k0 < DM_; k0 += 32) {
#pragma unroll
        for (int rep = 0; rep < 2; ++rep) {
            const int c = tid + rep * 256;
            const int row = c >> 2, kq = (c & 3) * 8;
            *(uint4*)(&As[row * FLDS + kq]) = *(const uint4*)(O   + (size_t)(row0 + row) * DM_ + k0 + kq);
            *(uint4*)(&Bs[row * FLDS + kq]) = *(const uint4*)(Wob + (size_t)(col0 + row) * DM_ + k0 + kq);
        }
        __syncthreads();
        short8 a[4], bfr[4];
#pragma unroll
        for (int mt = 0; mt < 4; ++mt)
            a[mt] = *(const short8*)(&As[(wm * 64 + mt * 16 + l16) * FLDS + q8]);
#pragma unroll
        for (int nt = 0; nt < 4; ++nt)
            bfr[nt] = *(const short8*)(&Bs[(wn * 64 + nt * 16 + l16) * FLDS + q8]);
#pragma unroll
        for (int mt = 0; mt < 4; ++mt)
#pragma unroll
            for (int nt = 0; nt < 4; ++nt)
                acc[mt][nt] = __builtin_amdgcn_mfma_f32_16x16x32_bf16(a[mt], bfr[nt], acc[mt][nt], 0, 0, 0);
        __syncthreads();
    }

    const float g = gatep[0];
    const int quad = lane >> 4;
#pragma unroll
    for (int mt = 0; mt < 4; ++mt) {
#pragma unroll
        for (int nt = 0; nt < 4; ++nt) {
            const int n = col0 + wn * 64 + nt * 16 + l16;
            const float bon = bo[n];
#pragma unroll
            for (int reg = 0; reg < 4; ++reg) {
                const int m = row0 + wm * 64 + mt * 16 + quad * 4 + reg;
                out[(size_t)m * NP_ + n] = Mi[(size_t)m * NP_ + n] + g * (acc[mt][nt][reg] + bon);
            }
        }
    }
}

extern "C" void kernel_launch(void* const* d_in, const int* in_sizes, int n_in,
                              void* d_out, int out_size, void* d_ws, size_t ws_size,
                              hipStream_t stream)
{
    (void)in_sizes; (void)n_in; (void)out_size;
    const float* Mi   = (const float*)d_in[0];
    const float* Wq   = (const float*)d_in[1];
    const float* Wk   = (const float*)d_in[2];
    const float* Wv   = (const float*)d_in[3];
    const float* Wo   = (const float*)d_in[4];
    const float* bo   = (const float*)d_in[5];
    const float* gate = (const float*)d_in[6];
    float* out  = (float*)d_out;
    float* Aout = out + (size_t)BC_ * NP_;

    // workspace layout (float-slots)
    float* ws = (float*)d_ws;
    u16*   Wob = (u16*)ws;                                     // 512x512 bf16
    u16*   Wvb = (u16*)(ws + 131072);                          // 512x512 bf16
    u16*   Mib = (u16*)(ws + 2 * 131072);                      // BC x 512 bf16
    float* Qf  = ws + 2 * 131072 + (size_t)BC_ * DM_ / 2;      // fp32
    float* Kf  = Qf + (size_t)BC_ * DM_;
    u16*   Vb  = (u16*)(Kf + (size_t)BC_ * DM_);               // bf16 V
    u16*   Of  = (u16*)(Kf + (size_t)BC_ * DM_ + (size_t)BC_ * DM_ / 2);  // bf16 O
    float* Sc  = Kf + (size_t)BC_ * DM_ + (size_t)BC_ * DM_;   // chunked scores

    const size_t fixed = 2 * 131072 + (size_t)BC_ * DM_ / 2 + 3 * (size_t)BC_ * DM_;
    const size_t ws_floats = ws_size / 4;
    size_t avail = (ws_floats > fixed) ? (ws_floats - fixed) : 0;
    int NB = (int)(avail / ((size_t)H_ * C_ * C_));
    if (NB < 1) NB = 1;
    if (NB > NBMAX) NB = NBMAX;

    f32_to_bf16<<<dim3(NP_ * DM_ / 1024), 256, 0, stream>>>(Wo, Wob);
    f32_to_bf16<<<dim3(NP_ * DM_ / 1024), 256, 0, stream>>>(Wv, Wvb);
    f32_to_bf16<<<dim3((int)((size_t)BC_ * NP_ / 1024)), 256, 0, stream>>>(Mi, Mib);

    qk_gemm<<<dim3(BC_ / BM, DM_ / BN, 2), 256, 0, stream>>>(Mi, Wq, Wk, Qf, Kf);
    v_gemm_mfma<<<dim3(BC_ / 128, DM_ / 128), 256, 0, stream>>>(Mib, Wvb, Vb);

    for (int b0 = 0; b0 < B_; b0 += NB) {
        const int nb = (B_ - b0 < NB) ? (B_ - b0) : NB;
        score_gemm<<<dim3(C_ / BM, C_ / BN, nb * 8), 256, 0, stream>>>(
            Qf + (size_t)b0 * C_ * DM_, Kf + (size_t)b0 * C_ * DM_, Sc);
        topk_attn<<<dim3(nb * C_), 256, 0, stream>>>(
            Sc, Vb + (size_t)b0 * C_ * DM_, Of + (size_t)b0 * C_ * DM_, Aout, b0);
    }

    final_gemm_mfma<<<dim3(BC_ / 128, NP_ / 128), 256, 0, stream>>>(
        Of, Wob, Mi, bo, gate, out);
}